// Round 1
// 599.319 us; speedup vs baseline: 1.0559x; 1.0559x over previous
//
#include <hip/hip_runtime.h>

// GCN 2-layer: N=100000, F=128 -> H=16 (relu) -> C=40, E=3200000.
//
// R2 restructure: replace the two fp32 atomic scatters (2 x 51.2M atomics,
// L2-atomic-throughput bound at ~307 Gops/s) with a dst-sorted CSR built once
// (int histogram -> scan -> permute) and two GATHER passes that accumulate in
// registers and store once per node. Aggregation WRITE_SIZE: 200MB -> 6.4MB.
//
// Math: norm(s->d) = dinv[s]*dinv[d], self-loop norm = dinv[n]^2.
//   h1p = (x@W1)*dinv            (pre-scaled => no dinv[src] gather per edge)
//   agg1[n] = dinv[n]*(h1p[n] + sum_{s in in(n)} h1p[s])
//   r1p[n]  = relu(agg1[n]+b1)*dinv[n]          (fused in gather1 epilogue)
//   agg2[n] = dinv[n]*(r1p[n] + sum r1p[s])
//   out[n]  = agg2[n]@W2 + b2                   (fused in gather2 epilogue)

#define N_NODES 100000
#define F_IN    128
#define H_MID   16
#define C_OUT   40
#define N_EDGES 3200000
#define NB      391          // ceil(N_NODES/256)

__global__ void k_zero(int* __restrict__ cnt) {
    int i = blockIdx.x * 256 + threadIdx.x;
    if (i < N_NODES) cnt[i] = 0;
}

__global__ void k_count(const int* __restrict__ dst, int* __restrict__ cnt) {
    int e = blockIdx.x * 256 + threadIdx.x;
    if (e < N_EDGES) atomicAdd(&cnt[dst[e]], 1);
}

// block-local exclusive scan of cnt -> rp, block sums -> part, dinv = rsqrt(1+cnt)
__global__ void __launch_bounds__(256) k_scan1(const int* __restrict__ cnt,
                                               int* __restrict__ rp,
                                               int* __restrict__ part,
                                               float* __restrict__ dinv) {
    __shared__ int s[256];
    int t = threadIdx.x;
    int i = blockIdx.x * 256 + t;
    int v = (i < N_NODES) ? cnt[i] : 0;
    s[t] = v;
    __syncthreads();
    for (int off = 1; off < 256; off <<= 1) {
        int x = (t >= off) ? s[t - off] : 0;
        __syncthreads();
        s[t] += x;
        __syncthreads();
    }
    if (i < N_NODES) {
        rp[i] = s[t] - v;                       // exclusive
        dinv[i] = rsqrtf(1.0f + (float)v);      // deg = indeg + self loop
    }
    if (t == 255) part[blockIdx.x] = s[255];
}

// exclusive scan of the NB block sums (single block)
__global__ void __launch_bounds__(512) k_scan2(int* __restrict__ part) {
    __shared__ int s[512];
    int t = threadIdx.x;
    int v = (t < NB) ? part[t] : 0;
    s[t] = v;
    __syncthreads();
    for (int off = 1; off < 512; off <<= 1) {
        int x = (t >= off) ? s[t - off] : 0;
        __syncthreads();
        s[t] += x;
        __syncthreads();
    }
    if (t < NB) part[t] = s[t] - v;
}

__global__ void k_scan3(int* __restrict__ rp, const int* __restrict__ part,
                        int* __restrict__ cursor) {
    int i = blockIdx.x * 256 + threadIdx.x;
    if (i < N_NODES) {
        int v = rp[i] + part[blockIdx.x];
        rp[i] = v;
        cursor[i] = v;
    }
    if (i == 0) rp[N_NODES] = N_EDGES;
}

// counting-sort edges by dst: es[pos] = src
__global__ void k_permute(const int* __restrict__ src, const int* __restrict__ dst,
                          int* __restrict__ cursor, int* __restrict__ es) {
    int e = blockIdx.x * 256 + threadIdx.x;
    if (e < N_EDGES) {
        int d = dst[e];
        int pos = atomicAdd(&cursor[d], 1);
        es[pos] = src[e];
    }
}

// 16 nodes per block, 256 threads = 16 nodes x 16 out-features.
// h1p = (x@W1) * dinv[node]
__global__ void __launch_bounds__(256) k_gemm1(
    const float* __restrict__ x, const float* __restrict__ W1,
    const float* __restrict__ dinv, float* __restrict__ h1p) {
    __shared__ float w[F_IN * H_MID];   // 8 KB
    __shared__ float xs[16 * 132];      // padded rows: no 128-stride conflicts
    int t = threadIdx.x;
    for (int i = t; i < F_IN * H_MID; i += 256) w[i] = W1[i];
    int tile = blockIdx.x;              // 6250 tiles, exact
    const float4* xg = (const float4*)(x + (size_t)tile * 16 * F_IN);
    float4* xs4 = (float4*)xs;          // row stride 33 float4
    for (int i = t; i < 512; i += 256) {
        int r = i >> 5, c4 = i & 31;
        xs4[r * 33 + c4] = xg[r * 32 + c4];
    }
    __syncthreads();
    int node = t >> 4, j = t & 15;
    const float* xr = xs + node * 132;
    float acc = 0.f;
#pragma unroll 8
    for (int k = 0; k < F_IN; ++k) acc += xr[k] * w[k * H_MID + j];
    int g = tile * 16 + node;
    h1p[(size_t)g * H_MID + j] = acc * dinv[g];
}

// gather layer 1 + fused relu/bias/prescale:
// r1p[n] = relu(dinv[n]*(h1p[n] + sum h1p[s]) + b1) * dinv[n]
__global__ void __launch_bounds__(256) k_gather1(
    const int* __restrict__ rp, const int* __restrict__ es,
    const float* __restrict__ dinv, const float* __restrict__ h1p,
    const float* __restrict__ b1, float* __restrict__ r1p) {
    int t = threadIdx.x;
    int node = blockIdx.x * 16 + (t >> 4), j = t & 15;
    float dv = dinv[node];
    int beg = rp[node], end = rp[node + 1];
    float acc = h1p[(size_t)node * H_MID + j];    // self loop (pre-scaled)
    int e = beg;
    for (; e + 4 <= end; e += 4) {
        int s0 = es[e], s1 = es[e + 1], s2 = es[e + 2], s3 = es[e + 3];
        float v0 = h1p[(size_t)s0 * H_MID + j];
        float v1 = h1p[(size_t)s1 * H_MID + j];
        float v2 = h1p[(size_t)s2 * H_MID + j];
        float v3 = h1p[(size_t)s3 * H_MID + j];
        acc += v0 + v1 + v2 + v3;
    }
    for (; e < end; ++e) acc += h1p[(size_t)es[e] * H_MID + j];
    float agg1 = dv * acc;
    r1p[(size_t)node * H_MID + j] = fmaxf(agg1 + b1[j], 0.f) * dv;
}

// gather layer 2 + fused @W2 + b2 epilogue (LDS).
__global__ void __launch_bounds__(256) k_gather2(
    const int* __restrict__ rp, const int* __restrict__ es,
    const float* __restrict__ dinv, const float* __restrict__ r1p,
    const float* __restrict__ W2, const float* __restrict__ b2,
    float* __restrict__ out) {
    __shared__ float w2[H_MID * C_OUT];   // 640
    __shared__ float a2[16 * 17];         // padded
    int t = threadIdx.x;
    for (int i = t; i < H_MID * C_OUT; i += 256) w2[i] = W2[i];
    int tile = blockIdx.x;
    int node = tile * 16 + (t >> 4), j = t & 15;
    float dv = dinv[node];
    int beg = rp[node], end = rp[node + 1];
    float acc = r1p[(size_t)node * H_MID + j];    // self loop (pre-scaled)
    int e = beg;
    for (; e + 4 <= end; e += 4) {
        int s0 = es[e], s1 = es[e + 1], s2 = es[e + 2], s3 = es[e + 3];
        float v0 = r1p[(size_t)s0 * H_MID + j];
        float v1 = r1p[(size_t)s1 * H_MID + j];
        float v2 = r1p[(size_t)s2 * H_MID + j];
        float v3 = r1p[(size_t)s3 * H_MID + j];
        acc += v0 + v1 + v2 + v3;
    }
    for (; e < end; ++e) acc += r1p[(size_t)es[e] * H_MID + j];
    a2[(t >> 4) * 17 + j] = dv * acc;
    __syncthreads();
    for (int idx = t; idx < 16 * C_OUT; idx += 256) {
        int nd = idx / C_OUT, c = idx % C_OUT;
        float s = b2[c];
#pragma unroll
        for (int jj = 0; jj < H_MID; ++jj) s += a2[nd * 17 + jj] * w2[jj * C_OUT + c];
        out[((size_t)tile * 16 + nd) * C_OUT + c] = s;
    }
}

extern "C" void kernel_launch(void* const* d_in, const int* in_sizes, int n_in,
                              void* d_out, int out_size, void* d_ws, size_t ws_size,
                              hipStream_t stream) {
    const float* x  = (const float*)d_in[0];
    const int*   ei = (const int*)d_in[1];     // [2, E]: row 0 = src, row 1 = dst
    const float* W1 = (const float*)d_in[2];
    const float* b1 = (const float*)d_in[3];
    const float* W2 = (const float*)d_in[4];
    const float* b2 = (const float*)d_in[5];
    float* out = (float*)d_out;

    const int* src = ei;
    const int* dst = ei + N_EDGES;

    // ws layout (4B units):
    //   rp[100352] | cnt/cursor[100352] | part[1024] | dinv[100352] |
    //   es[3.2M] | h1p[1.6M] | r1p[1.6M]   ~= 25.6 MiB
    int* rp     = (int*)d_ws;
    int* cnt    = rp + 100352;            // aliased: cursor after scan3
    int* part   = cnt + 100352;
    float* dinv = (float*)(part + 1024);
    int* es     = (int*)(dinv + 100352);
    float* h1p  = (float*)(es + N_EDGES);
    float* r1p  = h1p + (size_t)N_NODES * H_MID;

    const int B = 256;
    const int EB = (N_EDGES + B - 1) / B;     // 12500

    k_zero<<<NB, B, 0, stream>>>(cnt);
    k_count<<<EB, B, 0, stream>>>(dst, cnt);
    k_scan1<<<NB, B, 0, stream>>>(cnt, rp, part, dinv);
    k_scan2<<<1, 512, 0, stream>>>(part);
    k_scan3<<<NB, B, 0, stream>>>(rp, part, cnt);          // cnt becomes cursor
    k_gemm1<<<N_NODES / 16, B, 0, stream>>>(x, W1, dinv, h1p);
    k_permute<<<EB, B, 0, stream>>>(src, dst, cnt, es);
    k_gather1<<<N_NODES / 16, B, 0, stream>>>(rp, es, dinv, h1p, b1, r1p);
    k_gather2<<<N_NODES / 16, B, 0, stream>>>(rp, es, dinv, r1p, W2, b2, out);
}